// Round 2
// baseline (2375.964 us; speedup 1.0000x reference)
//
#include <hip/hip_runtime.h>
#include <math.h>

#define T_STEPS 512
#define IN_DIM  32
#define H       64
#define G4      256   // 4*H
#define NB      4     // batch rows per block

__device__ __forceinline__ float sigmoid_f(float x) {
    float e = __expf(-x);
    return __builtin_amdgcn_rcpf(1.0f + e);
}
__device__ __forceinline__ float tanh_f(float x) {
    float e = __expf(2.0f * x);
    return 1.0f - 2.0f * __builtin_amdgcn_rcpf(1.0f + e);
}

__launch_bounds__(256, 1)
__global__ void lstm_forecast_kernel(
    const float* __restrict__ seq, const int* __restrict__ line_id,
    const float* __restrict__ embed,
    const float* __restrict__ w_ih0, const float* __restrict__ w_hh0,
    const float* __restrict__ b_ih0, const float* __restrict__ b_hh0,
    const float* __restrict__ w_ih1, const float* __restrict__ w_hh1,
    const float* __restrict__ b_ih1, const float* __restrict__ b_hh1,
    const float* __restrict__ w1, const float* __restrict__ b1,
    const float* __restrict__ w2, const float* __restrict__ b2,
    float* __restrict__ out)
{
    const int tid = threadIdx.x;
    const int g   = tid;                  // gate row this thread owns
    const int b0  = blockIdx.x * NB;

    __shared__ __align__(16) float x_lds[NB][IN_DIM];
    __shared__ __align__(16) float h0_lds[NB][H];
    __shared__ __align__(16) float h1_lds[NB][H];
    __shared__ __align__(16) float gates_lds[NB][G4];

    // ---- per-thread weight rows in VGPRs (224 floats) ----
    float wih0[IN_DIM], whh0[H], wih1[H], whh1[H];
    {
        const float4* p = reinterpret_cast<const float4*>(w_ih0 + (size_t)g * IN_DIM);
        #pragma unroll
        for (int j = 0; j < IN_DIM/4; ++j) {
            float4 v = p[j];
            wih0[4*j+0]=v.x; wih0[4*j+1]=v.y; wih0[4*j+2]=v.z; wih0[4*j+3]=v.w;
        }
    }
    {
        const float4* p = reinterpret_cast<const float4*>(w_hh0 + (size_t)g * H);
        #pragma unroll
        for (int j = 0; j < H/4; ++j) {
            float4 v = p[j];
            whh0[4*j+0]=v.x; whh0[4*j+1]=v.y; whh0[4*j+2]=v.z; whh0[4*j+3]=v.w;
        }
    }
    {
        const float4* p = reinterpret_cast<const float4*>(w_ih1 + (size_t)g * H);
        #pragma unroll
        for (int j = 0; j < H/4; ++j) {
            float4 v = p[j];
            wih1[4*j+0]=v.x; wih1[4*j+1]=v.y; wih1[4*j+2]=v.z; wih1[4*j+3]=v.w;
        }
    }
    {
        const float4* p = reinterpret_cast<const float4*>(w_hh1 + (size_t)g * H);
        #pragma unroll
        for (int j = 0; j < H/4; ++j) {
            float4 v = p[j];
            whh1[4*j+0]=v.x; whh1[4*j+1]=v.y; whh1[4*j+2]=v.z; whh1[4*j+3]=v.w;
        }
    }
    const float bs0 = b_ih0[g] + b_hh0[g];
    const float bs1 = b_ih1[g] + b_hh1[g];

    const int ub = tid >> 6;              // update role: batch row
    const int uk = tid & 63;              // update role: hidden component

    h0_lds[ub][uk] = 0.0f;
    h1_lds[ub][uk] = 0.0f;
    float c0 = 0.0f, c1 = 0.0f;

    const int xb = tid >> 5;              // x-staging role (tid < 128)
    const int xi = tid & 31;
    float xreg = 0.0f;
    if (tid < NB * IN_DIM)
        xreg = seq[((size_t)(b0 + xb) * T_STEPS + 0) * IN_DIM + xi];

    #pragma unroll 1
    for (int t = 0; t < T_STEPS; ++t) {
        if (tid < NB * IN_DIM) x_lds[xb][xi] = xreg;
        __syncthreads();
        if (tid < NB * IN_DIM && (t + 1) < T_STEPS)
            xreg = seq[((size_t)(b0 + xb) * T_STEPS + (t + 1)) * IN_DIM + xi];

        // ---- phase 0: gates0[b][g] = bs0 + wih0·x[b] + whh0·h0[b] ----
        float acc[NB];
        #pragma unroll
        for (int b = 0; b < NB; ++b) {
            float a = bs0;
            const float4* xv = reinterpret_cast<const float4*>(&x_lds[b][0]);
            #pragma unroll
            for (int j = 0; j < IN_DIM/4; ++j) {
                float4 v = xv[j];
                a = fmaf(wih0[4*j+0], v.x, a);
                a = fmaf(wih0[4*j+1], v.y, a);
                a = fmaf(wih0[4*j+2], v.z, a);
                a = fmaf(wih0[4*j+3], v.w, a);
            }
            const float4* hv = reinterpret_cast<const float4*>(&h0_lds[b][0]);
            #pragma unroll
            for (int j = 0; j < H/4; ++j) {
                float4 v = hv[j];
                a = fmaf(whh0[4*j+0], v.x, a);
                a = fmaf(whh0[4*j+1], v.y, a);
                a = fmaf(whh0[4*j+2], v.z, a);
                a = fmaf(whh0[4*j+3], v.w, a);
            }
            acc[b] = a;
        }
        #pragma unroll
        for (int b = 0; b < NB; ++b) gates_lds[b][g] = acc[b];
        __syncthreads();

        // ---- update 0: thread (ub,uk) owns c0 ----
        {
            float ig = sigmoid_f(gates_lds[ub][       uk]);
            float fg = sigmoid_f(gates_lds[ub][  H  + uk]);
            float gg =    tanh_f(gates_lds[ub][2*H  + uk]);
            float og = sigmoid_f(gates_lds[ub][3*H  + uk]);
            c0 = fmaf(fg, c0, ig * gg);
            h0_lds[ub][uk] = og * tanh_f(c0);
        }
        __syncthreads();

        // ---- phase 1: gates1[b][g] = bs1 + wih1·h0new[b] + whh1·h1[b] ----
        #pragma unroll
        for (int b = 0; b < NB; ++b) {
            float a = bs1;
            const float4* h0v = reinterpret_cast<const float4*>(&h0_lds[b][0]);
            #pragma unroll
            for (int j = 0; j < H/4; ++j) {
                float4 v = h0v[j];
                a = fmaf(wih1[4*j+0], v.x, a);
                a = fmaf(wih1[4*j+1], v.y, a);
                a = fmaf(wih1[4*j+2], v.z, a);
                a = fmaf(wih1[4*j+3], v.w, a);
            }
            const float4* h1v = reinterpret_cast<const float4*>(&h1_lds[b][0]);
            #pragma unroll
            for (int j = 0; j < H/4; ++j) {
                float4 v = h1v[j];
                a = fmaf(whh1[4*j+0], v.x, a);
                a = fmaf(whh1[4*j+1], v.y, a);
                a = fmaf(whh1[4*j+2], v.z, a);
                a = fmaf(whh1[4*j+3], v.w, a);
            }
            acc[b] = a;
        }
        #pragma unroll
        for (int b = 0; b < NB; ++b) gates_lds[b][g] = acc[b];
        __syncthreads();

        // ---- update 1 ----
        {
            float ig = sigmoid_f(gates_lds[ub][       uk]);
            float fg = sigmoid_f(gates_lds[ub][  H  + uk]);
            float gg =    tanh_f(gates_lds[ub][2*H  + uk]);
            float og = sigmoid_f(gates_lds[ub][3*H  + uk]);
            c1 = fmaf(fg, c1, ig * gg);
            h1_lds[ub][uk] = og * tanh_f(c1);
        }
        __syncthreads();
    }

    // ---- head: fc1 = relu([h1, emb] @ w1.T + b1); out = fc1 @ w2.T + b2 ----
    {
        float a = b1[uk];
        #pragma unroll
        for (int j = 0; j < H; ++j)
            a = fmaf(w1[uk*(H+8) + j], h1_lds[ub][j], a);
        const int lid = line_id[b0 + ub];
        #pragma unroll
        for (int e = 0; e < 8; ++e)
            a = fmaf(w1[uk*(H+8) + H + e], embed[lid*8 + e], a);
        a = fmaxf(a, 0.0f);
        gates_lds[ub][uk] = a;   // reuse as fc1 buffer
    }
    __syncthreads();
    if (uk < 5) {
        float o = b2[uk];
        #pragma unroll
        for (int j = 0; j < H; ++j)
            o = fmaf(w2[uk*H + j], gates_lds[ub][j], o);
        out[(b0 + ub) * 5 + uk] = o;
    }
}

extern "C" void kernel_launch(void* const* d_in, const int* in_sizes, int n_in,
                              void* d_out, int out_size, void* d_ws, size_t ws_size,
                              hipStream_t stream) {
    const float* seq     = (const float*)d_in[0];
    const int*   line_id = (const int*)  d_in[1];
    const float* embed   = (const float*)d_in[2];
    const float* w_ih0   = (const float*)d_in[3];
    const float* w_hh0   = (const float*)d_in[4];
    const float* b_ih0   = (const float*)d_in[5];
    const float* b_hh0   = (const float*)d_in[6];
    const float* w_ih1   = (const float*)d_in[7];
    const float* w_hh1   = (const float*)d_in[8];
    const float* b_ih1   = (const float*)d_in[9];
    const float* b_hh1   = (const float*)d_in[10];
    const float* w1      = (const float*)d_in[11];
    const float* b1      = (const float*)d_in[12];
    const float* w2      = (const float*)d_in[13];
    const float* b2      = (const float*)d_in[14];
    float* out = (float*)d_out;

    lstm_forecast_kernel<<<dim3(1024 / NB), dim3(256), 0, stream>>>(
        seq, line_id, embed,
        w_ih0, w_hh0, b_ih0, b_hh0,
        w_ih1, w_hh1, b_ih1, b_hh1,
        w1, b1, w2, b2, out);
}

// Round 3
// 1502.139 us; speedup vs baseline: 1.5817x; 1.5817x over previous
//
#include <hip/hip_runtime.h>
#include <math.h>

#define T_STEPS 512
#define IN_DIM  32
#define H       64
#define NB      4     // batch rows per block

__device__ __forceinline__ float sigmoid_f(float x) {
    float e = __expf(-x);
    return __builtin_amdgcn_rcpf(1.0f + e);
}
__device__ __forceinline__ float tanh_f(float x) {
    float e = __expf(2.0f * x);
    return 1.0f - 2.0f * __builtin_amdgcn_rcpf(1.0f + e);
}

// Wave-specialized pipelined 2-layer LSTM:
//   waves 0-3 (tid<256): layer 0, gate row g = tid   (96 weight floats)
//   waves 4-7          : layer 1, gate row g = tid-256 (128 weight floats)
// Layer 1 runs one timestep behind layer 0; they share h0_lds read-only
// within a phase. 2 barriers per iteration.
__launch_bounds__(512, 2)
__global__ void lstm_forecast_kernel(
    const float* __restrict__ seq, const int* __restrict__ line_id,
    const float* __restrict__ embed,
    const float* __restrict__ w_ih0, const float* __restrict__ w_hh0,
    const float* __restrict__ b_ih0, const float* __restrict__ b_hh0,
    const float* __restrict__ w_ih1, const float* __restrict__ w_hh1,
    const float* __restrict__ b_ih1, const float* __restrict__ b_hh1,
    const float* __restrict__ w1, const float* __restrict__ b1,
    const float* __restrict__ w2, const float* __restrict__ b2,
    float* __restrict__ out)
{
    const int tid = threadIdx.x;
    const bool isA = (tid < 256);        // layer-0 group
    const int g   = tid & 255;           // gate row within layer
    const int b0  = blockIdx.x * NB;

    __shared__ __align__(16) float x_lds[NB][IN_DIM];
    __shared__ __align__(16) float h0_lds[NB][H];
    __shared__ __align__(16) float h1_lds[NB][H];
    __shared__ __align__(16) float gates0_lds[NB][4 * H];
    __shared__ __align__(16) float gates1_lds[NB][4 * H];

    // ---- per-thread weight row(s) in VGPRs ----
    // A: w[0..31] = w_ih0 row, w[32..95] = w_hh0 row   (96 used)
    // B: w[0..63] = w_ih1 row, w[64..127] = w_hh1 row  (128 used)
    float w[128];
    float bias;
    if (isA) {
        const float4* p = reinterpret_cast<const float4*>(w_ih0 + (size_t)g * IN_DIM);
        #pragma unroll
        for (int j = 0; j < IN_DIM / 4; ++j) {
            float4 v = p[j];
            w[4*j+0]=v.x; w[4*j+1]=v.y; w[4*j+2]=v.z; w[4*j+3]=v.w;
        }
        const float4* q = reinterpret_cast<const float4*>(w_hh0 + (size_t)g * H);
        #pragma unroll
        for (int j = 0; j < H / 4; ++j) {
            float4 v = q[j];
            w[32+4*j+0]=v.x; w[32+4*j+1]=v.y; w[32+4*j+2]=v.z; w[32+4*j+3]=v.w;
        }
        bias = b_ih0[g] + b_hh0[g];
    } else {
        const float4* p = reinterpret_cast<const float4*>(w_ih1 + (size_t)g * H);
        #pragma unroll
        for (int j = 0; j < H / 4; ++j) {
            float4 v = p[j];
            w[4*j+0]=v.x; w[4*j+1]=v.y; w[4*j+2]=v.z; w[4*j+3]=v.w;
        }
        const float4* q = reinterpret_cast<const float4*>(w_hh1 + (size_t)g * H);
        #pragma unroll
        for (int j = 0; j < H / 4; ++j) {
            float4 v = q[j];
            w[64+4*j+0]=v.x; w[64+4*j+1]=v.y; w[64+4*j+2]=v.z; w[64+4*j+3]=v.w;
        }
        bias = b_ih1[g] + b_hh1[g];
    }

    const int ub = g >> 6;               // update role: batch row
    const int uk = g & 63;               // update role: hidden component

    // init h state + first x tile
    if (isA) h0_lds[ub][uk] = 0.0f;
    else     h1_lds[ub][uk] = 0.0f;

    const int xb = g >> 5;               // x-stager role (A threads g<128)
    const int xi = g & 31;
    float xreg = 0.0f;
    if (isA && g < NB * IN_DIM) {
        x_lds[xb][xi] = seq[((size_t)(b0 + xb) * T_STEPS + 0) * IN_DIM + xi];
        xreg          = seq[((size_t)(b0 + xb) * T_STEPS + 1) * IN_DIM + xi];
    }
    float c = 0.0f;                      // c0 for A threads, c1 for B threads
    __syncthreads();

    // Pipeline: iteration t computes layer-0 step t (A) and layer-1 step t-1 (B).
    #pragma unroll 1
    for (int t = 0; t <= T_STEPS; ++t) {
        // ---- gate phase ----
        if (isA) {
            if (t < T_STEPS) {
                float acc[NB];
                #pragma unroll
                for (int b = 0; b < NB; ++b) {
                    float a = bias;
                    const float4* xv = reinterpret_cast<const float4*>(&x_lds[b][0]);
                    #pragma unroll
                    for (int j = 0; j < IN_DIM / 4; ++j) {
                        float4 v = xv[j];
                        a = fmaf(w[4*j+0], v.x, a);
                        a = fmaf(w[4*j+1], v.y, a);
                        a = fmaf(w[4*j+2], v.z, a);
                        a = fmaf(w[4*j+3], v.w, a);
                    }
                    const float4* hv = reinterpret_cast<const float4*>(&h0_lds[b][0]);
                    #pragma unroll
                    for (int j = 0; j < H / 4; ++j) {
                        float4 v = hv[j];
                        a = fmaf(w[32+4*j+0], v.x, a);
                        a = fmaf(w[32+4*j+1], v.y, a);
                        a = fmaf(w[32+4*j+2], v.z, a);
                        a = fmaf(w[32+4*j+3], v.w, a);
                    }
                    acc[b] = a;
                }
                #pragma unroll
                for (int b = 0; b < NB; ++b) gates0_lds[b][g] = acc[b];
            }
        } else {
            if (t >= 1) {
                float acc[NB];
                #pragma unroll
                for (int b = 0; b < NB; ++b) {
                    float a = bias;
                    const float4* h0v = reinterpret_cast<const float4*>(&h0_lds[b][0]);
                    #pragma unroll
                    for (int j = 0; j < H / 4; ++j) {
                        float4 v = h0v[j];
                        a = fmaf(w[4*j+0], v.x, a);
                        a = fmaf(w[4*j+1], v.y, a);
                        a = fmaf(w[4*j+2], v.z, a);
                        a = fmaf(w[4*j+3], v.w, a);
                    }
                    const float4* h1v = reinterpret_cast<const float4*>(&h1_lds[b][0]);
                    #pragma unroll
                    for (int j = 0; j < H / 4; ++j) {
                        float4 v = h1v[j];
                        a = fmaf(w[64+4*j+0], v.x, a);
                        a = fmaf(w[64+4*j+1], v.y, a);
                        a = fmaf(w[64+4*j+2], v.z, a);
                        a = fmaf(w[64+4*j+3], v.w, a);
                    }
                    acc[b] = a;
                }
                #pragma unroll
                for (int b = 0; b < NB; ++b) gates1_lds[b][g] = acc[b];
            }
        }
        __syncthreads();

        // ---- update phase ----
        if (isA) {
            if (t < T_STEPS) {
                float ig = sigmoid_f(gates0_lds[ub][        uk]);
                float fg = sigmoid_f(gates0_lds[ub][   H  + uk]);
                float gg =    tanh_f(gates0_lds[ub][ 2*H  + uk]);
                float og = sigmoid_f(gates0_lds[ub][ 3*H  + uk]);
                c = fmaf(fg, c, ig * gg);
                h0_lds[ub][uk] = og * tanh_f(c);
            }
            // stage x[t+1] (consumed by next iteration's gate phase)
            if (g < NB * IN_DIM && (t + 1) < T_STEPS) {
                x_lds[xb][xi] = xreg;
                if ((t + 2) < T_STEPS)
                    xreg = seq[((size_t)(b0 + xb) * T_STEPS + (t + 2)) * IN_DIM + xi];
            }
        } else {
            if (t >= 1) {
                float ig = sigmoid_f(gates1_lds[ub][        uk]);
                float fg = sigmoid_f(gates1_lds[ub][   H  + uk]);
                float gg =    tanh_f(gates1_lds[ub][ 2*H  + uk]);
                float og = sigmoid_f(gates1_lds[ub][ 3*H  + uk]);
                c = fmaf(fg, c, ig * gg);
                h1_lds[ub][uk] = og * tanh_f(c);
            }
        }
        __syncthreads();
    }

    // ---- head: fc1 = relu([h1, emb] @ w1.T + b1); out = fc1 @ w2.T + b2 ----
    if (isA) {
        float a = b1[uk];
        #pragma unroll
        for (int j = 0; j < H; ++j)
            a = fmaf(w1[uk*(H+8) + j], h1_lds[ub][j], a);
        const int lid = line_id[b0 + ub];
        #pragma unroll
        for (int e = 0; e < 8; ++e)
            a = fmaf(w1[uk*(H+8) + H + e], embed[lid*8 + e], a);
        gates0_lds[ub][uk] = fmaxf(a, 0.0f);   // reuse as fc1 buffer
    }
    __syncthreads();
    if (isA && uk < 5) {
        float o = b2[uk];
        #pragma unroll
        for (int j = 0; j < H; ++j)
            o = fmaf(w2[uk*H + j], gates0_lds[ub][j], o);
        out[(b0 + ub) * 5 + uk] = o;
    }
}

extern "C" void kernel_launch(void* const* d_in, const int* in_sizes, int n_in,
                              void* d_out, int out_size, void* d_ws, size_t ws_size,
                              hipStream_t stream) {
    const float* seq     = (const float*)d_in[0];
    const int*   line_id = (const int*)  d_in[1];
    const float* embed   = (const float*)d_in[2];
    const float* w_ih0   = (const float*)d_in[3];
    const float* w_hh0   = (const float*)d_in[4];
    const float* b_ih0   = (const float*)d_in[5];
    const float* b_hh0   = (const float*)d_in[6];
    const float* w_ih1   = (const float*)d_in[7];
    const float* w_hh1   = (const float*)d_in[8];
    const float* b_ih1   = (const float*)d_in[9];
    const float* b_hh1   = (const float*)d_in[10];
    const float* w1      = (const float*)d_in[11];
    const float* b1      = (const float*)d_in[12];
    const float* w2      = (const float*)d_in[13];
    const float* b2      = (const float*)d_in[14];
    float* out = (float*)d_out;

    lstm_forecast_kernel<<<dim3(1024 / NB), dim3(512), 0, stream>>>(
        seq, line_id, embed,
        w_ih0, w_hh0, b_ih0, b_hh0,
        w_ih1, w_hh1, b_ih1, b_hh1,
        w1, b1, w2, b2, out);
}

// Round 4
// 864.554 us; speedup vs baseline: 2.7482x; 1.7375x over previous
//
#include <hip/hip_runtime.h>
#include <math.h>

#define T_STEPS 512
#define IN_DIM  32
#define H       64
#define NB      2     // batch rows per block

typedef _Float16 h2 __attribute__((ext_vector_type(2)));
typedef _Float16 h8 __attribute__((ext_vector_type(8)));

#if __has_builtin(__builtin_amdgcn_fdot2)
__device__ __forceinline__ float fdot2(h2 a, h2 b, float c) {
    return __builtin_amdgcn_fdot2(a, b, c, false);
}
#else
__device__ __forceinline__ float fdot2(h2 a, h2 b, float c) {
    return c + (float)a.x * (float)b.x + (float)a.y * (float)b.y;
}
#endif

__device__ __forceinline__ h2 mk2(_Float16 a, _Float16 b) { h2 r; r.x = a; r.y = b; return r; }

__device__ __forceinline__ float sigmoid_f(float x) {
    float e = __expf(-x);
    return __builtin_amdgcn_rcpf(1.0f + e);
}
__device__ __forceinline__ float tanh_f(float x) {
    float e = __expf(2.0f * x);
    return 1.0f - 2.0f * __builtin_amdgcn_rcpf(1.0f + e);
}

// Wave-specialized pipelined 2-layer LSTM, f16-packed operands, f32 accumulate.
//   waves 0-3 (tid<256): layer 0, gate row g = tid    (16+32 = 48 h2 weights)
//   waves 4-7          : layer 1, gate row g = tid-256 (32+32 = 64 h2 weights)
// Layer 1 runs one timestep behind layer 0. 2 barriers/iter.
// grid=512 (NB=2) -> 2 blocks/CU for cross-block barrier overlap.
__launch_bounds__(512, 4)
__global__ void lstm_forecast_kernel(
    const float* __restrict__ seq, const int* __restrict__ line_id,
    const float* __restrict__ embed,
    const float* __restrict__ w_ih0, const float* __restrict__ w_hh0,
    const float* __restrict__ b_ih0, const float* __restrict__ b_hh0,
    const float* __restrict__ w_ih1, const float* __restrict__ w_hh1,
    const float* __restrict__ b_ih1, const float* __restrict__ b_hh1,
    const float* __restrict__ w1, const float* __restrict__ b1,
    const float* __restrict__ w2, const float* __restrict__ b2,
    float* __restrict__ out)
{
    const int tid = threadIdx.x;
    const bool isA = (tid < 256);
    const int g    = tid & 255;
    const int b0   = blockIdx.x * NB;

    __shared__ __align__(16) h2 x_lds[NB][IN_DIM / 2];   // f16 x
    __shared__ __align__(16) h2 h0_lds[NB][H / 2];       // f16 h0
    __shared__ __align__(16) h2 h1_lds[NB][H / 2];       // f16 h1
    __shared__ __align__(16) float gates0_lds[NB][4 * H];
    __shared__ __align__(16) float gates1_lds[NB][4 * H];

    // ---- per-thread weight rows, f16-packed ----
    // A: wih[0..15] = w_ih0 row (32), whh[0..31] = w_hh0 row (64)
    // B: wih[0..31] = w_ih1 row (64), whh[0..31] = w_hh1 row (64)
    h2 wih[32], whh[32];
    float bias;
    if (isA) {
        const float4* p = reinterpret_cast<const float4*>(w_ih0 + (size_t)g * IN_DIM);
        #pragma unroll
        for (int j = 0; j < 8; ++j) {
            float4 v = p[j];
            wih[2*j+0] = mk2((_Float16)v.x, (_Float16)v.y);
            wih[2*j+1] = mk2((_Float16)v.z, (_Float16)v.w);
        }
        const float4* q = reinterpret_cast<const float4*>(w_hh0 + (size_t)g * H);
        #pragma unroll
        for (int j = 0; j < 16; ++j) {
            float4 v = q[j];
            whh[2*j+0] = mk2((_Float16)v.x, (_Float16)v.y);
            whh[2*j+1] = mk2((_Float16)v.z, (_Float16)v.w);
        }
        bias = b_ih0[g] + b_hh0[g];
    } else {
        const float4* p = reinterpret_cast<const float4*>(w_ih1 + (size_t)g * H);
        #pragma unroll
        for (int j = 0; j < 16; ++j) {
            float4 v = p[j];
            wih[2*j+0] = mk2((_Float16)v.x, (_Float16)v.y);
            wih[2*j+1] = mk2((_Float16)v.z, (_Float16)v.w);
        }
        const float4* q = reinterpret_cast<const float4*>(w_hh1 + (size_t)g * H);
        #pragma unroll
        for (int j = 0; j < 16; ++j) {
            float4 v = q[j];
            whh[2*j+0] = mk2((_Float16)v.x, (_Float16)v.y);
            whh[2*j+1] = mk2((_Float16)v.z, (_Float16)v.w);
        }
        bias = b_ih1[g] + b_hh1[g];
    }

    // init h state (f16 zeros)
    if (isA) { if (g < NB * H / 2) ((h2*)h0_lds)[g] = mk2((_Float16)0.f, (_Float16)0.f); }
    else     { if (g < NB * H / 2) ((h2*)h1_lds)[g] = mk2((_Float16)0.f, (_Float16)0.f); }

    // x stagers: A threads g in [128,160). j = g-128: sb = batch, sp = float2-pair
    const int sj = g - 128;
    const int sb = (sj >> 4) & 1;
    const int sp = sj & 15;
    const bool stager = isA && (sj >= 0) && (sj < NB * IN_DIM / 2);
    const float2* seq2 = reinterpret_cast<const float2*>(seq);
    const size_t sbase = (size_t)(b0 + sb) * T_STEPS * (IN_DIM / 2) + sp;
    float2 xreg = make_float2(0.f, 0.f);
    if (stager) {
        float2 v0 = seq2[sbase];                       // t = 0
        x_lds[sb][sp] = mk2((_Float16)v0.x, (_Float16)v0.y);
        xreg = seq2[sbase + (IN_DIM / 2)];             // t = 1
    }

    float c = 0.0f;            // c0 for A updaters, c1 for B updaters
    const int ub = g >> 6;     // update role (g < 128): batch row
    const int uk = g & 63;     // update role: hidden component
    __syncthreads();

    // iteration t: layer-0 step t (A, t<512) and layer-1 step t-1 (B, t>=1)
    #pragma unroll 1
    for (int t = 0; t <= T_STEPS; ++t) {
        // ---- gate phase ----
        if (isA) {
            if (t < T_STEPS) {
                #pragma unroll
                for (int b = 0; b < NB; ++b) {
                    float a = bias;
                    const h8* xv = reinterpret_cast<const h8*>(&x_lds[b][0]);  // 4 x h8
                    #pragma unroll
                    for (int j = 0; j < 4; ++j) {
                        h8 v = xv[j];
                        #pragma unroll
                        for (int k = 0; k < 4; ++k)
                            a = fdot2(wih[4*j + k], mk2(v[2*k], v[2*k+1]), a);
                    }
                    const h8* hv = reinterpret_cast<const h8*>(&h0_lds[b][0]); // 8 x h8
                    #pragma unroll
                    for (int j = 0; j < 8; ++j) {
                        h8 v = hv[j];
                        #pragma unroll
                        for (int k = 0; k < 4; ++k)
                            a = fdot2(whh[4*j + k], mk2(v[2*k], v[2*k+1]), a);
                    }
                    gates0_lds[b][g] = a;
                }
            }
        } else {
            if (t >= 1) {
                #pragma unroll
                for (int b = 0; b < NB; ++b) {
                    float a = bias;
                    const h8* h0v = reinterpret_cast<const h8*>(&h0_lds[b][0]);
                    #pragma unroll
                    for (int j = 0; j < 8; ++j) {
                        h8 v = h0v[j];
                        #pragma unroll
                        for (int k = 0; k < 4; ++k)
                            a = fdot2(wih[4*j + k], mk2(v[2*k], v[2*k+1]), a);
                    }
                    const h8* h1v = reinterpret_cast<const h8*>(&h1_lds[b][0]);
                    #pragma unroll
                    for (int j = 0; j < 8; ++j) {
                        h8 v = h1v[j];
                        #pragma unroll
                        for (int k = 0; k < 4; ++k)
                            a = fdot2(whh[4*j + k], mk2(v[2*k], v[2*k+1]), a);
                    }
                    gates1_lds[b][g] = a;
                }
            }
        }
        __syncthreads();

        // ---- update phase ----
        if (isA) {
            if (t < T_STEPS && g < NB * H) {
                float ig = sigmoid_f(gates0_lds[ub][        uk]);
                float fg = sigmoid_f(gates0_lds[ub][   H  + uk]);
                float gg =    tanh_f(gates0_lds[ub][ 2*H  + uk]);
                float og = sigmoid_f(gates0_lds[ub][ 3*H  + uk]);
                c = fmaf(fg, c, ig * gg);
                ((_Float16*)h0_lds)[ub * H + uk] = (_Float16)(og * tanh_f(c));
            }
            if (stager && (t + 1) < T_STEPS) {
                x_lds[sb][sp] = mk2((_Float16)xreg.x, (_Float16)xreg.y);
                if ((t + 2) < T_STEPS)
                    xreg = seq2[sbase + (size_t)(t + 2) * (IN_DIM / 2)];
            }
        } else {
            if (t >= 1 && g < NB * H) {
                float ig = sigmoid_f(gates1_lds[ub][        uk]);
                float fg = sigmoid_f(gates1_lds[ub][   H  + uk]);
                float gg =    tanh_f(gates1_lds[ub][ 2*H  + uk]);
                float og = sigmoid_f(gates1_lds[ub][ 3*H  + uk]);
                c = fmaf(fg, c, ig * gg);
                ((_Float16*)h1_lds)[ub * H + uk] = (_Float16)(og * tanh_f(c));
            }
        }
        __syncthreads();
    }

    // ---- head: fc1 = relu([h1, emb] @ w1.T + b1); out = fc1 @ w2.T + b2 ----
    if (tid < NB * H) {
        float a = b1[uk];
        #pragma unroll
        for (int j = 0; j < H; ++j)
            a = fmaf(w1[uk*(H+8) + j], (float)((const _Float16*)h1_lds)[ub * H + j], a);
        const int lid = line_id[b0 + ub];
        #pragma unroll
        for (int e = 0; e < 8; ++e)
            a = fmaf(w1[uk*(H+8) + H + e], embed[lid*8 + e], a);
        gates0_lds[ub][uk] = fmaxf(a, 0.0f);   // fc1 buffer
    }
    __syncthreads();
    if (tid < NB * H && uk < 5) {
        float o = b2[uk];
        #pragma unroll
        for (int j = 0; j < H; ++j)
            o = fmaf(w2[uk*H + j], gates0_lds[ub][j], o);
        out[(b0 + ub) * 5 + uk] = o;
    }
}

extern "C" void kernel_launch(void* const* d_in, const int* in_sizes, int n_in,
                              void* d_out, int out_size, void* d_ws, size_t ws_size,
                              hipStream_t stream) {
    const float* seq     = (const float*)d_in[0];
    const int*   line_id = (const int*)  d_in[1];
    const float* embed   = (const float*)d_in[2];
    const float* w_ih0   = (const float*)d_in[3];
    const float* w_hh0   = (const float*)d_in[4];
    const float* b_ih0   = (const float*)d_in[5];
    const float* b_hh0   = (const float*)d_in[6];
    const float* w_ih1   = (const float*)d_in[7];
    const float* w_hh1   = (const float*)d_in[8];
    const float* b_ih1   = (const float*)d_in[9];
    const float* b_hh1   = (const float*)d_in[10];
    const float* w1      = (const float*)d_in[11];
    const float* b1      = (const float*)d_in[12];
    const float* w2      = (const float*)d_in[13];
    const float* b2      = (const float*)d_in[14];
    float* out = (float*)d_out;

    lstm_forecast_kernel<<<dim3(1024 / NB), dim3(512), 0, stream>>>(
        seq, line_id, embed,
        w_ih0, w_hh0, b_ih0, b_hh0,
        w_ih1, w_hh1, b_ih1, b_hh1,
        w1, b1, w2, b2, out);
}